// Round 3
// baseline (413.361 us; speedup 1.0000x reference)
//
#include <hip/hip_runtime.h>
#include <hip/hip_bf16.h>

// ===== Problem constants =====
// B=8, N=1025, C=768, H=12, HD=64
constexpr int NTOK   = 1025;
constexpr int M      = 8 * NTOK;      // 8200 tokens
constexpr int MP     = 8320;          // 65 * 128 padded rows
constexpr int KDIM   = 768;
constexpr int NQKV   = 2304;
constexpr int NKVPAD = 1088;          // 17*64 padded kv length for vT
constexpr float SCALE = 0.125f;       // 64^-0.5
constexpr float SCALEL2 = 0.125f * 1.44269504f; // fold log2(e): scores in log2 domain

using bf16x8 = __attribute__((ext_vector_type(8))) short;
using f32x4  = __attribute__((ext_vector_type(4))) float;

__device__ __forceinline__ f32x4 mfma_bf16(bf16x8 a, bf16x8 b, f32x4 c) {
  return __builtin_amdgcn_mfma_f32_16x16x32_bf16(a, b, c, 0, 0, 0);
}

__device__ __forceinline__ void gl16(const void* g, void* l) {
  __builtin_amdgcn_global_load_lds(
      (const __attribute__((address_space(1))) void*)g,
      (__attribute__((address_space(3))) void*)l, 16, 0, 0);
}

// ===== Workspace layout (bytes), all 256-aligned =====
constexpr size_t SZ_X     = (size_t)MP * KDIM * 2;        // 12,779,520
constexpr size_t SZ_WQ    = (size_t)NQKV * KDIM * 2;      // 3,538,944
constexpr size_t SZ_PW    = (size_t)KDIM * KDIM * 2;      // 1,179,648
constexpr size_t SZ_QK    = (size_t)96 * NTOK * 64 * 2;   // 12,595,200
constexpr size_t SZ_VT    = (size_t)96 * 64 * NKVPAD * 2; // 13,369,344
constexpr size_t OFF_XHI  = 0;
constexpr size_t OFF_XLO  = OFF_XHI + SZ_X;
constexpr size_t OFF_WQHI = OFF_XLO + SZ_X;
constexpr size_t OFF_PWHI = OFF_WQHI + SZ_WQ;
constexpr size_t OFF_PWLO = OFF_PWHI + SZ_PW;
constexpr size_t OFF_Q    = OFF_PWLO + SZ_PW;
constexpr size_t OFF_K    = OFF_Q + SZ_QK;
constexpr size_t OFF_VT   = OFF_K + SZ_QK;
constexpr size_t OFF_AO   = OFF_VT + SZ_VT;
// total ~83 MB

// ===== K0a: fp32 -> (hi,lo) bf16 split, zero tail =====
__global__ void k_split(const float* __restrict__ src, __hip_bfloat16* __restrict__ hi,
                        __hip_bfloat16* __restrict__ lo, int n_src, int n_dst) {
  int i = blockIdx.x * 256 + threadIdx.x;
  if (i >= n_dst) return;
  float v = (i < n_src) ? src[i] : 0.0f;
  __hip_bfloat16 h = __float2bfloat16(v);
  hi[i] = h;
  lo[i] = __float2bfloat16(v - __bfloat162float(h));
}

// K0b: fp32 -> bf16 (hi only)
__global__ void k_tobf16(const float* __restrict__ src, __hip_bfloat16* __restrict__ dst,
                         int n) {
  int i = blockIdx.x * 256 + threadIdx.x;
  if (i >= n) return;
  dst[i] = __float2bfloat16(src[i]);
}

// zero vT pad columns (keys 1025..1087) so PV MFMA never sees NaN garbage
__global__ void k_zero_vt(__hip_bfloat16* __restrict__ vt) {
  int i = blockIdx.x * 256 + threadIdx.x;
  constexpr int NPADC = NKVPAD - NTOK; // 63
  if (i >= 96 * 64 * NPADC) return;
  int r = i / NPADC;
  int c = NTOK + (i - r * NPADC);
  vt[(size_t)r * NKVPAD + c] = __float2bfloat16(0.0f);
}

// ===== GEMM core: 128x128 tile, BK=32, 2-term split, swizzled LDS =====
// SPLIT_A=1: acc = Ah*Bh + Al*Bh   (Asec = A_lo, row base mBase)
// SPLIT_A=0: acc = Ah*Bh + Ah*Bl   (Asec = B_lo, row base nBase)
// LDS swizzle (conflict-free ds_read_b128 with linear global_load_lds dest):
//   chunk c (16B) holds global (row=c>>2, slot=(c&3)^((row>>1)&3)) of the tile;
//   4-lane groups still fetch the same contiguous 64B from global (coalesced).
// EPI=0: QKV -> bias + RoPE -> q,k ([bh][t][d] bf16) and vT ([bh][d][t_pad] bf16)
// EPI=1: proj -> bias -> fp32 d_out
template <int EPI, bool SPLIT_A>
__global__ __launch_bounds__(256) void k_gemm(
    const __hip_bfloat16* __restrict__ Ahi, const __hip_bfloat16* __restrict__ Asec,
    const __hip_bfloat16* __restrict__ Bhi, const float* __restrict__ bias,
    const float* __restrict__ sinp, const float* __restrict__ cosp,
    __hip_bfloat16* __restrict__ o_q, __hip_bfloat16* __restrict__ o_k,
    __hip_bfloat16* __restrict__ o_vt, float* __restrict__ o_f32) {
  const int tid = threadIdx.x;
  const int w = tid >> 6, lane = tid & 63;
  const int wm = w >> 1, wn = w & 1;
  const int l15 = lane & 15, q4 = lane >> 4;
  const int mBase = blockIdx.y * 128, nBase = blockIdx.x * 128;

  __shared__ __hip_bfloat16 sm[3 * 4096]; // three [128][32] bf16 tiles
  char* s0 = (char*)sm;          // A_hi
  char* s1 = s0 + 8192;          // SPLIT_A ? A_lo : B_lo
  char* s2 = s0 + 16384;         // B_hi

  const char* p0 = (const char*)Ahi + (size_t)mBase * (KDIM * 2);
  const char* p1 = (const char*)Asec + (size_t)(SPLIT_A ? mBase : nBase) * (KDIM * 2);
  const char* p2 = (const char*)Bhi + (size_t)nBase * (KDIM * 2);

  const int slog = ((tid & 3) ^ ((tid >> 3) & 3)) << 4; // staged slot byte offset
  const int ph = ((q4 ^ ((l15 >> 1) & 3)) << 4);        // fragment slot byte offset

  f32x4 acc[4][4] = {};

  for (int kt = 0; kt < KDIM / 32; ++kt) {
    const int kofs = kt * 64; // bytes into each row
#pragma unroll
    for (int i = 0; i < 2; ++i) {
      const int c = i * 256 + tid; // 16B chunk index, 512 per tile
      const size_t rb = (size_t)(i * 64 + (tid >> 2)) * (KDIM * 2) + slog + kofs;
      gl16(p0 + rb, s0 + (size_t)c * 16);
      gl16(p1 + rb, s1 + (size_t)c * 16);
      gl16(p2 + rb, s2 + (size_t)c * 16);
    }
    __syncthreads();
    bf16x8 a0[4], a1[4], b0[4], b1[4];
#pragma unroll
    for (int mt = 0; mt < 4; ++mt) {
      const int r = wm * 64 + mt * 16 + l15;
      a0[mt] = *(const bf16x8*)(s0 + r * 64 + ph);
      if (SPLIT_A) a1[mt] = *(const bf16x8*)(s1 + r * 64 + ph);
    }
#pragma unroll
    for (int nt = 0; nt < 4; ++nt) {
      const int r = wn * 64 + nt * 16 + l15;
      b0[nt] = *(const bf16x8*)(s2 + r * 64 + ph);
      if (!SPLIT_A) b1[nt] = *(const bf16x8*)(s1 + r * 64 + ph);
    }
#pragma unroll
    for (int mt = 0; mt < 4; ++mt)
#pragma unroll
      for (int nt = 0; nt < 4; ++nt) {
        acc[mt][nt] = mfma_bf16(a0[mt], b0[nt], acc[mt][nt]);
        if (SPLIT_A)
          acc[mt][nt] = mfma_bf16(a1[mt], b0[nt], acc[mt][nt]);
        else
          acc[mt][nt] = mfma_bf16(a0[mt], b1[nt], acc[mt][nt]);
      }
    __syncthreads();
  }

  // epilogue; C layout: col = lane&15, row = 4*(lane>>4)+j
#pragma unroll
  for (int mt = 0; mt < 4; ++mt)
#pragma unroll
    for (int j = 0; j < 4; ++j) {
      const int gm = mBase + wm * 64 + mt * 16 + q4 * 4 + j;
      if (gm >= M) continue;
      if (EPI == 0) {
        const int b = gm / NTOK;
        const int t = gm - b * NTOK;
#pragma unroll
        for (int nt = 0; nt < 4; ++nt) {
          const int gc = nBase + wn * 64 + nt * 16 + l15;
          float v = acc[mt][nt][j] + bias[gc];
          const int three = gc / 768;
          const int hd = gc - three * 768;
          const int h = hd >> 6, d = hd & 63;
          const int bh = b * 12 + h;
          if (three == 2) {
            o_vt[((size_t)bh * 64 + d) * NKVPAD + t] = __float2bfloat16(v);
          } else {
            if (t > 0) {
              const float pv = acc[mt][nt ^ 2][j] + bias[gc ^ 32];
              const int so = (t - 1) * 64 + d;
              v = v * cosp[so] + ((d < 32) ? -pv : pv) * sinp[so];
            }
            const __hip_bfloat16 bv = __float2bfloat16(v);
            if (three == 0)
              o_q[((size_t)bh * NTOK + t) * 64 + d] = bv;
            else
              o_k[((size_t)bh * NTOK + t) * 64 + d] = bv;
          }
        }
      } else {
#pragma unroll
        for (int nt = 0; nt < 4; ++nt) {
          const int gc = nBase + wn * 64 + nt * 16 + l15;
          o_f32[(size_t)gm * 768 + gc] = acc[mt][nt][j] + bias[gc];
        }
      }
    }
}

// ===== K2: flash attention, 4 waves x 16 q-rows, KV tiles of 64 =====
// Grid: 1632 = 8 XCD chunks * 12 heads * 17 q-blocks (XCD-aware remap for
// K/V L2 locality). Scores kept in log2 domain (exp2). Defer-max (T13, THR=8
// log2-units) skips O-rescale when tile max doesn't grow. Last KV tile peeled
// so the 16 full tiles run mask/clamp-free.
__global__ __launch_bounds__(256) void k_attn(
    const __hip_bfloat16* __restrict__ Q, const __hip_bfloat16* __restrict__ Kk,
    const __hip_bfloat16* __restrict__ VT, __hip_bfloat16* __restrict__ ao) {
  __shared__ __hip_bfloat16 Pl[4][16][72]; // per-wave P tile
  const int tid = threadIdx.x, w = tid >> 6, lane = tid & 63;
  const int l15 = lane & 15, q4 = lane >> 4;
  const int id = blockIdx.x;
  const int xcd = id & 7, sub = id >> 3;    // sub 0..203
  const int bh = xcd * 12 + sub / 17;
  const int qb = (sub % 17) * 64 + w * 16;  // this wave's 16 q-rows
  const size_t qbase = (size_t)bh * NTOK * 64;

  // Q fragments (rows clamped; pad rows are discarded at store)
  bf16x8 qa[2];
  {
    int t = qb + l15;
    if (t > NTOK - 1) t = NTOK - 1;
#pragma unroll
    for (int ks = 0; ks < 2; ++ks)
      qa[ks] = *(const bf16x8*)(Q + qbase + (size_t)t * 64 + ks * 32 + q4 * 8);
  }

  f32x4 accO[4] = {};
  float mrun[4], lrun[4];
#pragma unroll
  for (int j = 0; j < 4; ++j) {
    mrun[j] = -1e30f;
    lrun[j] = 0.0f;
  }

  auto step = [&](int kb0, bool last) {
    // S = Q K^T  (lane holds S[row=q4*4+j][col=nt*16+l15])
    f32x4 s[4] = {};
    {
      bf16x8 kfr[2][4];
#pragma unroll
      for (int nt = 0; nt < 4; ++nt) {
        int krow = kb0 + nt * 16 + l15;
        if (last && krow > NTOK - 1) krow = NTOK - 1;
#pragma unroll
        for (int ks = 0; ks < 2; ++ks)
          kfr[ks][nt] =
              *(const bf16x8*)(Kk + qbase + (size_t)krow * 64 + ks * 32 + q4 * 8);
      }
#pragma unroll
      for (int nt = 0; nt < 4; ++nt)
#pragma unroll
        for (int ks = 0; ks < 2; ++ks)
          s[nt] = mfma_bf16(qa[ks], kfr[ks][nt], s[nt]);
    }
    // row maxes (rows live in 16-lane groups; reduce via shfl_xor 1..8)
    float sv[4][4], pmax[4];
#pragma unroll
    for (int j = 0; j < 4; ++j) {
      float m0 = -1e30f;
#pragma unroll
      for (int nt = 0; nt < 4; ++nt) {
        float v = s[nt][j] * SCALEL2;
        if (last && (kb0 + nt * 16 + l15 > NTOK - 1)) v = -1e30f;
        sv[j][nt] = v;
        m0 = fmaxf(m0, v);
      }
#pragma unroll
      for (int off = 1; off < 16; off <<= 1) m0 = fmaxf(m0, __shfl_xor(m0, off));
      pmax[j] = m0;
    }
    // defer-max: only rescale when some row's max grew past THR
    bool ok = true;
#pragma unroll
    for (int j = 0; j < 4; ++j) ok = ok && (pmax[j] <= mrun[j] + 8.0f);
    if (!__all(ok)) {
#pragma unroll
      for (int j = 0; j < 4; ++j) {
        const float mnew = fmaxf(mrun[j], pmax[j]);
        const float fsc = exp2f(mrun[j] - mnew);
        lrun[j] *= fsc;
        mrun[j] = mnew;
#pragma unroll
        for (int nd = 0; nd < 4; ++nd) accO[nd][j] *= fsc;
      }
    }
    // P = exp2(S - m), row sums, stage P to LDS for the PV transpose
#pragma unroll
    for (int j = 0; j < 4; ++j) {
      float sum = 0.0f;
#pragma unroll
      for (int nt = 0; nt < 4; ++nt) {
        const float p = exp2f(sv[j][nt] - mrun[j]);
        sum += p;
        Pl[w][q4 * 4 + j][nt * 16 + l15] = __float2bfloat16(p);
      }
#pragma unroll
      for (int off = 1; off < 16; off <<= 1) sum += __shfl_xor(sum, off);
      lrun[j] += sum;
    }
    // PV (wave-private LDS; compiler orders ds_write->ds_read via lgkmcnt)
    bf16x8 pa[2], vf[2][4];
#pragma unroll
    for (int ks = 0; ks < 2; ++ks)
      pa[ks] = *(const bf16x8*)&Pl[w][l15][ks * 32 + q4 * 8];
#pragma unroll
    for (int nd = 0; nd < 4; ++nd)
#pragma unroll
      for (int ks = 0; ks < 2; ++ks)
        vf[ks][nd] = *(const bf16x8*)(VT + ((size_t)bh * 64 + nd * 16 + l15) * NKVPAD +
                                      kb0 + ks * 32 + q4 * 8);
#pragma unroll
    for (int nd = 0; nd < 4; ++nd)
#pragma unroll
      for (int ks = 0; ks < 2; ++ks)
        accO[nd] = mfma_bf16(pa[ks], vf[ks][nd], accO[nd]);
  };

  for (int kt = 0; kt < 16; ++kt) step(kt * 64, false);
  step(1024, true);

  // store attn_out bf16 at [b*1025+t][h*64+d]
  const int b = bh / 12, h = bh - (bh / 12) * 12;
#pragma unroll
  for (int j = 0; j < 4; ++j) {
    const int t = qb + q4 * 4 + j;
    if (t > NTOK - 1) continue;
    const float inv = 1.0f / lrun[j];
    const size_t ro = ((size_t)(b * NTOK + t)) * 768 + h * 64;
#pragma unroll
    for (int nd = 0; nd < 4; ++nd) {
      const int d = nd * 16 + l15;
      ao[ro + d] = __float2bfloat16(accO[nd][j] * inv);
    }
  }
}

extern "C" void kernel_launch(void* const* d_in, const int* in_sizes, int n_in,
                              void* d_out, int out_size, void* d_ws, size_t ws_size,
                              hipStream_t stream) {
  const float* x = (const float*)d_in[0];
  const float* sinp = (const float*)d_in[1];
  const float* cosp = (const float*)d_in[2];
  const float* qkvw = (const float*)d_in[3];
  const float* qkvb = (const float*)d_in[4];
  const float* projw = (const float*)d_in[5];
  const float* projb = (const float*)d_in[6];

  char* ws = (char*)d_ws;
  __hip_bfloat16* xhi = (__hip_bfloat16*)(ws + OFF_XHI);
  __hip_bfloat16* xlo = (__hip_bfloat16*)(ws + OFF_XLO);
  __hip_bfloat16* wqhi = (__hip_bfloat16*)(ws + OFF_WQHI);
  __hip_bfloat16* pwhi = (__hip_bfloat16*)(ws + OFF_PWHI);
  __hip_bfloat16* pwlo = (__hip_bfloat16*)(ws + OFF_PWLO);
  __hip_bfloat16* qb = (__hip_bfloat16*)(ws + OFF_Q);
  __hip_bfloat16* kb = (__hip_bfloat16*)(ws + OFF_K);
  __hip_bfloat16* vt = (__hip_bfloat16*)(ws + OFF_VT);
  __hip_bfloat16* ao = (__hip_bfloat16*)(ws + OFF_AO);

  // K0: converts (x gets zero tail to MP rows; qkv_w hi only; proj_w hi+lo)
  {
    int n_src = M * KDIM, n_dst = MP * KDIM;
    k_split<<<(n_dst + 255) / 256, 256, 0, stream>>>(x, xhi, xlo, n_src, n_dst);
    int nw = NQKV * KDIM;
    k_tobf16<<<(nw + 255) / 256, 256, 0, stream>>>(qkvw, wqhi, nw);
    int np = KDIM * KDIM;
    k_split<<<(np + 255) / 256, 256, 0, stream>>>(projw, pwhi, pwlo, np, np);
    int nz = 96 * 64 * (NKVPAD - NTOK);
    k_zero_vt<<<(nz + 255) / 256, 256, 0, stream>>>(vt);
  }
  // K1: QKV GEMM (x split, w single) + bias + RoPE -> q, k, vT
  k_gemm<0, true><<<dim3(NQKV / 128, MP / 128), 256, 0, stream>>>(
      xhi, xlo, wqhi, qkvb, sinp, cosp, qb, kb, vt, nullptr);
  // K2: flash attention -> attn_out bf16 (1632 = 8*12*17 blocks)
  k_attn<<<dim3(1632), 256, 0, stream>>>(qb, kb, vt, ao);
  // K3: proj GEMM (attn_out single, w split) + bias -> fp32 out
  k_gemm<1, false><<<dim3(KDIM / 128, MP / 128), 256, 0, stream>>>(
      ao, pwlo, pwhi, projb, nullptr, nullptr, nullptr, nullptr, nullptr,
      (float*)d_out);
}

// Round 4
// 388.213 us; speedup vs baseline: 1.0648x; 1.0648x over previous
//
#include <hip/hip_runtime.h>
#include <hip/hip_bf16.h>

// ===== Problem constants =====
// B=8, N=1025, C=768, H=12, HD=64
constexpr int NTOK   = 1025;
constexpr int M      = 8 * NTOK;      // 8200 tokens
constexpr int MP     = 8320;          // 65 * 128 padded rows
constexpr int KDIM   = 768;
constexpr int NQKV   = 2304;
constexpr int NKVPAD = 1088;          // 17*64 padded kv length for vT
constexpr float SCALEL2 = 0.125f * 1.44269504f; // 64^-0.5 * log2(e)

using bf16x8 = __attribute__((ext_vector_type(8))) short;
using f32x4  = __attribute__((ext_vector_type(4))) float;

__device__ __forceinline__ f32x4 mfma_bf16(bf16x8 a, bf16x8 b, f32x4 c) {
  return __builtin_amdgcn_mfma_f32_16x16x32_bf16(a, b, c, 0, 0, 0);
}

__device__ __forceinline__ void gl16(const void* g, void* l) {
  __builtin_amdgcn_global_load_lds(
      (const __attribute__((address_space(1))) void*)g,
      (__attribute__((address_space(3))) void*)l, 16, 0, 0);
}

// ===== Workspace layout (bytes), all 256-aligned =====
constexpr size_t SZ_X     = (size_t)MP * KDIM * 2;        // 12,779,520
constexpr size_t SZ_WQ    = (size_t)NQKV * KDIM * 2;      // 3,538,944
constexpr size_t SZ_PW    = (size_t)KDIM * KDIM * 2;      // 1,179,648
constexpr size_t SZ_QK    = (size_t)96 * NTOK * 64 * 2;   // 12,595,200
constexpr size_t SZ_VT    = (size_t)96 * 64 * NKVPAD * 2; // 13,369,344
constexpr size_t OFF_XHI  = 0;
constexpr size_t OFF_XLO  = OFF_XHI + SZ_X;
constexpr size_t OFF_WQHI = OFF_XLO + SZ_X;
constexpr size_t OFF_PWHI = OFF_WQHI + SZ_WQ;
constexpr size_t OFF_PWLO = OFF_PWHI + SZ_PW;
constexpr size_t OFF_Q    = OFF_PWLO + SZ_PW;
constexpr size_t OFF_K    = OFF_Q + SZ_QK;
constexpr size_t OFF_VT   = OFF_K + SZ_QK;
constexpr size_t OFF_AO   = OFF_VT + SZ_VT;
// total ~83 MB

// ===== K0a: fp32 -> (hi,lo) bf16 split, zero tail =====
__global__ void k_split(const float* __restrict__ src, __hip_bfloat16* __restrict__ hi,
                        __hip_bfloat16* __restrict__ lo, int n_src, int n_dst) {
  int i = blockIdx.x * 256 + threadIdx.x;
  if (i >= n_dst) return;
  float v = (i < n_src) ? src[i] : 0.0f;
  __hip_bfloat16 h = __float2bfloat16(v);
  hi[i] = h;
  lo[i] = __float2bfloat16(v - __bfloat162float(h));
}

// K0b: fp32 -> bf16 (hi only)
__global__ void k_tobf16(const float* __restrict__ src, __hip_bfloat16* __restrict__ dst,
                         int n) {
  int i = blockIdx.x * 256 + threadIdx.x;
  if (i >= n) return;
  dst[i] = __float2bfloat16(src[i]);
}

// zero vT pad columns (keys 1025..1087) so PV MFMA never sees NaN garbage
__global__ void k_zero_vt(__hip_bfloat16* __restrict__ vt) {
  int i = blockIdx.x * 256 + threadIdx.x;
  constexpr int NPADC = NKVPAD - NTOK; // 63
  if (i >= 96 * 64 * NPADC) return;
  int r = i / NPADC;
  int c = NTOK + (i - r * NPADC);
  vt[(size_t)r * NKVPAD + c] = __float2bfloat16(0.0f);
}

// ===== GEMM core: 128x128 tile, BK=32, 2-term split, swizzled LDS =====
// SPLIT_A=1: acc = Ah*Bh + Al*Bh   (Asec = A_lo, row base mBase)
// SPLIT_A=0: acc = Ah*Bh + Ah*Bl   (Asec = B_lo, row base nBase)
// LDS swizzle (conflict-free ds_read_b128 with linear global_load_lds dest):
//   chunk c (16B) holds global (row=c>>2, slot=(c&3)^((row>>1)&3)) of the tile;
//   4-lane groups still fetch the same contiguous 64B from global (coalesced).
// EPI=0: QKV -> bias + RoPE -> q,k ([bh][t][d] bf16) and vT ([bh][d][t_pad] bf16)
// EPI=1: proj -> bias -> fp32 d_out
template <int EPI, bool SPLIT_A>
__global__ __launch_bounds__(256) void k_gemm(
    const __hip_bfloat16* __restrict__ Ahi, const __hip_bfloat16* __restrict__ Asec,
    const __hip_bfloat16* __restrict__ Bhi, const float* __restrict__ bias,
    const float* __restrict__ sinp, const float* __restrict__ cosp,
    __hip_bfloat16* __restrict__ o_q, __hip_bfloat16* __restrict__ o_k,
    __hip_bfloat16* __restrict__ o_vt, float* __restrict__ o_f32) {
  const int tid = threadIdx.x;
  const int w = tid >> 6, lane = tid & 63;
  const int wm = w >> 1, wn = w & 1;
  const int l15 = lane & 15, q4 = lane >> 4;
  const int mBase = blockIdx.y * 128, nBase = blockIdx.x * 128;

  __shared__ __hip_bfloat16 sm[3 * 4096]; // three [128][32] bf16 tiles
  char* s0 = (char*)sm;          // A_hi
  char* s1 = s0 + 8192;          // SPLIT_A ? A_lo : B_lo
  char* s2 = s0 + 16384;         // B_hi

  const char* p0 = (const char*)Ahi + (size_t)mBase * (KDIM * 2);
  const char* p1 = (const char*)Asec + (size_t)(SPLIT_A ? mBase : nBase) * (KDIM * 2);
  const char* p2 = (const char*)Bhi + (size_t)nBase * (KDIM * 2);

  const int slog = ((tid & 3) ^ ((tid >> 3) & 3)) << 4; // staged slot byte offset
  const int ph = ((q4 ^ ((l15 >> 1) & 3)) << 4);        // fragment slot byte offset

  f32x4 acc[4][4] = {};

  for (int kt = 0; kt < KDIM / 32; ++kt) {
    const int kofs = kt * 64; // bytes into each row
#pragma unroll
    for (int i = 0; i < 2; ++i) {
      const int c = i * 256 + tid; // 16B chunk index, 512 per tile
      const size_t rb = (size_t)(i * 64 + (tid >> 2)) * (KDIM * 2) + slog + kofs;
      gl16(p0 + rb, s0 + (size_t)c * 16);
      gl16(p1 + rb, s1 + (size_t)c * 16);
      gl16(p2 + rb, s2 + (size_t)c * 16);
    }
    __syncthreads();
    bf16x8 a0[4], a1[4], b0[4], b1[4];
#pragma unroll
    for (int mt = 0; mt < 4; ++mt) {
      const int r = wm * 64 + mt * 16 + l15;
      a0[mt] = *(const bf16x8*)(s0 + r * 64 + ph);
      if (SPLIT_A) a1[mt] = *(const bf16x8*)(s1 + r * 64 + ph);
    }
#pragma unroll
    for (int nt = 0; nt < 4; ++nt) {
      const int r = wn * 64 + nt * 16 + l15;
      b0[nt] = *(const bf16x8*)(s2 + r * 64 + ph);
      if (!SPLIT_A) b1[nt] = *(const bf16x8*)(s1 + r * 64 + ph);
    }
#pragma unroll
    for (int mt = 0; mt < 4; ++mt)
#pragma unroll
      for (int nt = 0; nt < 4; ++nt) {
        acc[mt][nt] = mfma_bf16(a0[mt], b0[nt], acc[mt][nt]);
        if (SPLIT_A)
          acc[mt][nt] = mfma_bf16(a1[mt], b0[nt], acc[mt][nt]);
        else
          acc[mt][nt] = mfma_bf16(a0[mt], b1[nt], acc[mt][nt]);
      }
    __syncthreads();
  }

  // epilogue; C layout: col = lane&15, row = 4*(lane>>4)+j
#pragma unroll
  for (int mt = 0; mt < 4; ++mt)
#pragma unroll
    for (int j = 0; j < 4; ++j) {
      const int gm = mBase + wm * 64 + mt * 16 + q4 * 4 + j;
      if (gm >= M) continue;
      if (EPI == 0) {
        const int b = gm / NTOK;
        const int t = gm - b * NTOK;
#pragma unroll
        for (int nt = 0; nt < 4; ++nt) {
          const int gc = nBase + wn * 64 + nt * 16 + l15;
          float v = acc[mt][nt][j] + bias[gc];
          const int three = gc / 768;
          const int hd = gc - three * 768;
          const int h = hd >> 6, d = hd & 63;
          const int bh = b * 12 + h;
          if (three == 2) {
            o_vt[((size_t)bh * 64 + d) * NKVPAD + t] = __float2bfloat16(v);
          } else {
            if (t > 0) {
              const float pv = acc[mt][nt ^ 2][j] + bias[gc ^ 32];
              const int so = (t - 1) * 64 + d;
              v = v * cosp[so] + ((d < 32) ? -pv : pv) * sinp[so];
            }
            const __hip_bfloat16 bv = __float2bfloat16(v);
            if (three == 0)
              o_q[((size_t)bh * NTOK + t) * 64 + d] = bv;
            else
              o_k[((size_t)bh * NTOK + t) * 64 + d] = bv;
          }
        }
      } else {
#pragma unroll
        for (int nt = 0; nt < 4; ++nt) {
          const int gc = nBase + wn * 64 + nt * 16 + l15;
          o_f32[(size_t)gm * 768 + gc] = acc[mt][nt][j] + bias[gc];
        }
      }
    }
}

// ===== K2: flash attention, 4 waves x 32 q-rows, KV tiles of 64 =====
// Grid: 864 = 8 XCD chunks * 12 heads * 9 q-blocks (XCD-aware remap keeps one
// head's K/V inside one XCD's L2). Scores in log2 domain (exp2). Defer-max
// (THR=8 log2-units) skips O-rescale when tile max doesn't grow. Last KV tile
// peeled so the 16 full tiles run mask-free. Register pipeline: V(t) loads
// issued at step top (hide under QK+softmax), K(t+1) double-buffered prefetch
// (hide under softmax+PV). s_setprio(1) around MFMA clusters (T5).
__global__ __launch_bounds__(256) void k_attn(
    const __hip_bfloat16* __restrict__ Q, const __hip_bfloat16* __restrict__ Kk,
    const __hip_bfloat16* __restrict__ VT, __hip_bfloat16* __restrict__ ao) {
  __shared__ __hip_bfloat16 Pl[4][32][72]; // per-wave P tile
  const int tid = threadIdx.x, w = tid >> 6, lane = tid & 63;
  const int l15 = lane & 15, q4 = lane >> 4;
  const int id = blockIdx.x;
  const int xcd = id & 7, sub = id >> 3;   // sub 0..107
  const int hh = sub / 9;                  // head-within-xcd 0..11
  const int bh = xcd * 12 + hh;
  const int qb = (sub - hh * 9) * 128 + w * 32;
  const size_t qbase = (size_t)bh * NTOK * 64;
  const __hip_bfloat16* Kb = Kk + qbase;
  const __hip_bfloat16* Vb = VT + (size_t)bh * 64 * NKVPAD;

  // Q fragments (rows clamped; pad rows are discarded at store)
  bf16x8 qa[2][2];
#pragma unroll
  for (int mt = 0; mt < 2; ++mt) {
    int t = qb + mt * 16 + l15;
    if (t > NTOK - 1) t = NTOK - 1;
#pragma unroll
    for (int ks = 0; ks < 2; ++ks)
      qa[mt][ks] = *(const bf16x8*)(Q + qbase + (size_t)t * 64 + ks * 32 + q4 * 8);
  }

  f32x4 accO[2][4] = {};
  float mrun[2][4], lrun[2][4];
#pragma unroll
  for (int mt = 0; mt < 2; ++mt)
#pragma unroll
    for (int j = 0; j < 4; ++j) {
      mrun[mt][j] = -1e30f;
      lrun[mt][j] = 0.0f;
    }

  bf16x8 kcur[2][4], knxt[2][4];
  // preload K tile 0 (rows 0..63, in range)
#pragma unroll
  for (int nt = 0; nt < 4; ++nt)
#pragma unroll
    for (int ks = 0; ks < 2; ++ks)
      kcur[ks][nt] =
          *(const bf16x8*)(Kb + (size_t)(nt * 16 + l15) * 64 + ks * 32 + q4 * 8);

  auto step = [&](int kt, bool last) {
    const int kb0 = kt * 64;
    // V(t) loads — issued first; latency hides under QK + softmax
    bf16x8 vf[2][4];
#pragma unroll
    for (int nd = 0; nd < 4; ++nd)
#pragma unroll
      for (int ks = 0; ks < 2; ++ks)
        vf[ks][nd] = *(const bf16x8*)(Vb + (size_t)(nd * 16 + l15) * NKVPAD + kb0 +
                                      ks * 32 + q4 * 8);
    // K(t+1) prefetch into double buffer — hides under softmax + PV
    if (!last) {
#pragma unroll
      for (int nt = 0; nt < 4; ++nt) {
        int krow = kb0 + 64 + nt * 16 + l15;
        if (krow > NTOK - 1) krow = NTOK - 1;
#pragma unroll
        for (int ks = 0; ks < 2; ++ks)
          knxt[ks][nt] = *(const bf16x8*)(Kb + (size_t)krow * 64 + ks * 32 + q4 * 8);
      }
    }
    // S = Q K^T (lane holds S[row = mt*16 + q4*4+j][col = nt*16 + l15])
    f32x4 s[2][4] = {};
    __builtin_amdgcn_s_setprio(1);
#pragma unroll
    for (int mt = 0; mt < 2; ++mt)
#pragma unroll
      for (int nt = 0; nt < 4; ++nt)
#pragma unroll
        for (int ks = 0; ks < 2; ++ks)
          s[mt][nt] = mfma_bf16(qa[mt][ks], kcur[ks][nt], s[mt][nt]);
    __builtin_amdgcn_s_setprio(0);
    // scale to log2 domain (+ mask dead key columns on the peeled tile)
#pragma unroll
    for (int mt = 0; mt < 2; ++mt)
#pragma unroll
      for (int nt = 0; nt < 4; ++nt) {
        const bool dead = last && (kb0 + nt * 16 + l15 > NTOK - 1);
#pragma unroll
        for (int j = 0; j < 4; ++j)
          s[mt][nt][j] = dead ? -1e30f : s[mt][nt][j] * SCALEL2;
      }
    // row maxes via 16-lane shfl reduce
    float pmax[2][4];
    bool ok = true;
#pragma unroll
    for (int mt = 0; mt < 2; ++mt)
#pragma unroll
      for (int j = 0; j < 4; ++j) {
        float m0 =
            fmaxf(fmaxf(s[mt][0][j], s[mt][1][j]), fmaxf(s[mt][2][j], s[mt][3][j]));
#pragma unroll
        for (int off = 1; off < 16; off <<= 1) m0 = fmaxf(m0, __shfl_xor(m0, off));
        pmax[mt][j] = m0;
        ok = ok && (m0 <= mrun[mt][j] + 8.0f);
      }
    // defer-max: rescale only when some row's max grew past THR
    if (!__all(ok)) {
#pragma unroll
      for (int mt = 0; mt < 2; ++mt)
#pragma unroll
        for (int j = 0; j < 4; ++j) {
          const float mnew = fmaxf(mrun[mt][j], pmax[mt][j]);
          const float fsc = exp2f(mrun[mt][j] - mnew);
          lrun[mt][j] *= fsc;
          mrun[mt][j] = mnew;
#pragma unroll
          for (int nd = 0; nd < 4; ++nd) accO[mt][nd][j] *= fsc;
        }
    }
    // P = exp2(S - m), row sums, stage P to LDS for the PV transpose
#pragma unroll
    for (int mt = 0; mt < 2; ++mt)
#pragma unroll
      for (int j = 0; j < 4; ++j) {
        float sum = 0.0f;
        const int row = mt * 16 + q4 * 4 + j;
#pragma unroll
        for (int nt = 0; nt < 4; ++nt) {
          const float p = exp2f(s[mt][nt][j] - mrun[mt][j]);
          sum += p;
          Pl[w][row][nt * 16 + l15] = __float2bfloat16(p);
        }
#pragma unroll
        for (int off = 1; off < 16; off <<= 1) sum += __shfl_xor(sum, off);
        lrun[mt][j] += sum;
      }
    // PV (wave-private LDS; compiler orders ds_write->ds_read via lgkmcnt)
    bf16x8 pa[2][2];
#pragma unroll
    for (int mt = 0; mt < 2; ++mt)
#pragma unroll
      for (int ks = 0; ks < 2; ++ks)
        pa[mt][ks] = *(const bf16x8*)&Pl[w][mt * 16 + l15][ks * 32 + q4 * 8];
    __builtin_amdgcn_s_setprio(1);
#pragma unroll
    for (int mt = 0; mt < 2; ++mt)
#pragma unroll
      for (int nd = 0; nd < 4; ++nd)
#pragma unroll
        for (int ks = 0; ks < 2; ++ks)
          accO[mt][nd] = mfma_bf16(pa[mt][ks], vf[ks][nd], accO[mt][nd]);
    __builtin_amdgcn_s_setprio(0);
    // rotate K double buffer
    if (!last) {
#pragma unroll
      for (int nt = 0; nt < 4; ++nt)
#pragma unroll
        for (int ks = 0; ks < 2; ++ks)
          kcur[ks][nt] = knxt[ks][nt];
    }
  };

  for (int kt = 0; kt < 16; ++kt) step(kt, false);
  step(16, true);

  // store attn_out bf16 at [b*1025+t][h*64+d]
  const int b = bh / 12, h = bh - (bh / 12) * 12;
#pragma unroll
  for (int mt = 0; mt < 2; ++mt)
#pragma unroll
    for (int j = 0; j < 4; ++j) {
      const int t = qb + mt * 16 + q4 * 4 + j;
      if (t > NTOK - 1) continue;
      const float inv = 1.0f / lrun[mt][j];
      const size_t ro = ((size_t)(b * NTOK + t)) * 768 + h * 64;
#pragma unroll
      for (int nd = 0; nd < 4; ++nd) {
        const int d = nd * 16 + l15;
        ao[ro + d] = __float2bfloat16(accO[mt][nd][j] * inv);
      }
    }
}

extern "C" void kernel_launch(void* const* d_in, const int* in_sizes, int n_in,
                              void* d_out, int out_size, void* d_ws, size_t ws_size,
                              hipStream_t stream) {
  const float* x = (const float*)d_in[0];
  const float* sinp = (const float*)d_in[1];
  const float* cosp = (const float*)d_in[2];
  const float* qkvw = (const float*)d_in[3];
  const float* qkvb = (const float*)d_in[4];
  const float* projw = (const float*)d_in[5];
  const float* projb = (const float*)d_in[6];

  char* ws = (char*)d_ws;
  __hip_bfloat16* xhi = (__hip_bfloat16*)(ws + OFF_XHI);
  __hip_bfloat16* xlo = (__hip_bfloat16*)(ws + OFF_XLO);
  __hip_bfloat16* wqhi = (__hip_bfloat16*)(ws + OFF_WQHI);
  __hip_bfloat16* pwhi = (__hip_bfloat16*)(ws + OFF_PWHI);
  __hip_bfloat16* pwlo = (__hip_bfloat16*)(ws + OFF_PWLO);
  __hip_bfloat16* qb = (__hip_bfloat16*)(ws + OFF_Q);
  __hip_bfloat16* kb = (__hip_bfloat16*)(ws + OFF_K);
  __hip_bfloat16* vt = (__hip_bfloat16*)(ws + OFF_VT);
  __hip_bfloat16* ao = (__hip_bfloat16*)(ws + OFF_AO);

  // K0: converts (x gets zero tail to MP rows; qkv_w hi only; proj_w hi+lo)
  {
    int n_src = M * KDIM, n_dst = MP * KDIM;
    k_split<<<(n_dst + 255) / 256, 256, 0, stream>>>(x, xhi, xlo, n_src, n_dst);
    int nw = NQKV * KDIM;
    k_tobf16<<<(nw + 255) / 256, 256, 0, stream>>>(qkvw, wqhi, nw);
    int np = KDIM * KDIM;
    k_split<<<(np + 255) / 256, 256, 0, stream>>>(projw, pwhi, pwlo, np, np);
    int nz = 96 * 64 * (NKVPAD - NTOK);
    k_zero_vt<<<(nz + 255) / 256, 256, 0, stream>>>(vt);
  }
  // K1: QKV GEMM (x split, w single) + bias + RoPE -> q, k, vT
  k_gemm<0, true><<<dim3(NQKV / 128, MP / 128), 256, 0, stream>>>(
      xhi, xlo, wqhi, qkvb, sinp, cosp, qb, kb, vt, nullptr);
  // K2: flash attention -> attn_out bf16 (864 = 8 XCD * 12 heads * 9 qblocks)
  k_attn<<<dim3(864), 256, 0, stream>>>(qb, kb, vt, ao);
  // K3: proj GEMM (attn_out single, w split) + bias -> fp32 out
  k_gemm<1, false><<<dim3(KDIM / 128, MP / 128), 256, 0, stream>>>(
      ao, pwlo, pwhi, projb, nullptr, nullptr, nullptr, nullptr, nullptr,
      (float*)d_out);
}

// Round 5
// 329.442 us; speedup vs baseline: 1.2547x; 1.1784x over previous
//
#include <hip/hip_runtime.h>
#include <hip/hip_bf16.h>

// ===== Problem constants =====
// B=8, N=1025, C=768, H=12, HD=64
constexpr int NTOK   = 1025;
constexpr int M      = 8 * NTOK;      // 8200 tokens
constexpr int MP     = 8320;          // 65 * 128 padded rows
constexpr int KDIM   = 768;
constexpr int NQKV   = 2304;
constexpr int NKVPAD = 1088;          // 17*64 padded kv length for vT
constexpr float SCALEL2 = 0.125f * 1.44269504f; // 64^-0.5 * log2(e), folded into K

using bf16x8 = __attribute__((ext_vector_type(8))) short;
using f32x4  = __attribute__((ext_vector_type(4))) float;

__device__ __forceinline__ f32x4 mfma_bf16(bf16x8 a, bf16x8 b, f32x4 c) {
  return __builtin_amdgcn_mfma_f32_16x16x32_bf16(a, b, c, 0, 0, 0);
}

__device__ __forceinline__ void gl16(const void* g, void* l) {
  __builtin_amdgcn_global_load_lds(
      (const __attribute__((address_space(1))) void*)g,
      (__attribute__((address_space(3))) void*)l, 16, 0, 0);
}

// ===== Workspace layout (bytes), all 256-aligned =====
constexpr size_t SZ_X     = (size_t)MP * KDIM * 2;        // 12,779,520
constexpr size_t SZ_WQ    = (size_t)NQKV * KDIM * 2;      // 3,538,944
constexpr size_t SZ_PW    = (size_t)KDIM * KDIM * 2;      // 1,179,648
constexpr size_t SZ_QK    = (size_t)96 * NTOK * 64 * 2;   // 12,595,200
constexpr size_t SZ_VT    = (size_t)96 * 64 * NKVPAD * 2; // 13,369,344
constexpr size_t OFF_XHI  = 0;
constexpr size_t OFF_XLO  = OFF_XHI + SZ_X;
constexpr size_t OFF_WQHI = OFF_XLO + SZ_X;
constexpr size_t OFF_PWHI = OFF_WQHI + SZ_WQ;
constexpr size_t OFF_PWLO = OFF_PWHI + SZ_PW;
constexpr size_t OFF_Q    = OFF_PWLO + SZ_PW;
constexpr size_t OFF_K    = OFF_Q + SZ_QK;
constexpr size_t OFF_VT   = OFF_K + SZ_QK;
constexpr size_t OFF_AO   = OFF_VT + SZ_VT;
// total ~83 MB

// ===== K0a: fp32 -> (hi,lo) bf16 split, zero tail =====
__global__ void k_split(const float* __restrict__ src, __hip_bfloat16* __restrict__ hi,
                        __hip_bfloat16* __restrict__ lo, int n_src, int n_dst) {
  int i = blockIdx.x * 256 + threadIdx.x;
  if (i >= n_dst) return;
  float v = (i < n_src) ? src[i] : 0.0f;
  __hip_bfloat16 h = __float2bfloat16(v);
  hi[i] = h;
  lo[i] = __float2bfloat16(v - __bfloat162float(h));
}

// K0b: fp32 -> bf16 (hi only)
__global__ void k_tobf16(const float* __restrict__ src, __hip_bfloat16* __restrict__ dst,
                         int n) {
  int i = blockIdx.x * 256 + threadIdx.x;
  if (i >= n) return;
  dst[i] = __float2bfloat16(src[i]);
}

// zero vT pad columns (keys 1025..1087) so PV MFMA never sees NaN garbage
__global__ void k_zero_vt(__hip_bfloat16* __restrict__ vt) {
  int i = blockIdx.x * 256 + threadIdx.x;
  constexpr int NPADC = NKVPAD - NTOK; // 63
  if (i >= 96 * 64 * NPADC) return;
  int r = i / NPADC;
  int c = NTOK + (i - r * NPADC);
  vt[(size_t)r * NKVPAD + c] = __float2bfloat16(0.0f);
}

// ===== GEMM core: 128x128 tile, BK=32, 2-term split, swizzled LDS =====
// SPLIT_A=1: acc = Ah*Bh + Al*Bh   (Asec = A_lo, row base mBase)
// SPLIT_A=0: acc = Ah*Bh + Ah*Bl   (Asec = B_lo, row base nBase)
// LDS swizzle (conflict-free ds_read_b128 with linear global_load_lds dest):
//   chunk c (16B) holds global (row=c>>2, slot=(c&3)^((row>>1)&3)) of the tile;
//   4-lane groups still fetch the same contiguous 64B from global (coalesced).
// EPI=0: QKV -> bias + RoPE -> q,k ([bh][t][d] bf16; K pre-scaled by SCALEL2)
//        and vT ([bh][d][t_pad] bf16)
// EPI=1: proj -> bias -> fp32 d_out
template <int EPI, bool SPLIT_A>
__global__ __launch_bounds__(256) void k_gemm(
    const __hip_bfloat16* __restrict__ Ahi, const __hip_bfloat16* __restrict__ Asec,
    const __hip_bfloat16* __restrict__ Bhi, const float* __restrict__ bias,
    const float* __restrict__ sinp, const float* __restrict__ cosp,
    __hip_bfloat16* __restrict__ o_q, __hip_bfloat16* __restrict__ o_k,
    __hip_bfloat16* __restrict__ o_vt, float* __restrict__ o_f32) {
  const int tid = threadIdx.x;
  const int w = tid >> 6, lane = tid & 63;
  const int wm = w >> 1, wn = w & 1;
  const int l15 = lane & 15, q4 = lane >> 4;
  const int mBase = blockIdx.y * 128, nBase = blockIdx.x * 128;

  __shared__ __hip_bfloat16 sm[3 * 4096]; // three [128][32] bf16 tiles
  char* s0 = (char*)sm;          // A_hi
  char* s1 = s0 + 8192;          // SPLIT_A ? A_lo : B_lo
  char* s2 = s0 + 16384;         // B_hi

  const char* p0 = (const char*)Ahi + (size_t)mBase * (KDIM * 2);
  const char* p1 = (const char*)Asec + (size_t)(SPLIT_A ? mBase : nBase) * (KDIM * 2);
  const char* p2 = (const char*)Bhi + (size_t)nBase * (KDIM * 2);

  const int slog = ((tid & 3) ^ ((tid >> 3) & 3)) << 4; // staged slot byte offset
  const int ph = ((q4 ^ ((l15 >> 1) & 3)) << 4);        // fragment slot byte offset

  f32x4 acc[4][4] = {};

  for (int kt = 0; kt < KDIM / 32; ++kt) {
    const int kofs = kt * 64; // bytes into each row
#pragma unroll
    for (int i = 0; i < 2; ++i) {
      const int c = i * 256 + tid; // 16B chunk index, 512 per tile
      const size_t rb = (size_t)(i * 64 + (tid >> 2)) * (KDIM * 2) + slog + kofs;
      gl16(p0 + rb, s0 + (size_t)c * 16);
      gl16(p1 + rb, s1 + (size_t)c * 16);
      gl16(p2 + rb, s2 + (size_t)c * 16);
    }
    __syncthreads();
    bf16x8 a0[4], a1[4], b0[4], b1[4];
#pragma unroll
    for (int mt = 0; mt < 4; ++mt) {
      const int r = wm * 64 + mt * 16 + l15;
      a0[mt] = *(const bf16x8*)(s0 + r * 64 + ph);
      if (SPLIT_A) a1[mt] = *(const bf16x8*)(s1 + r * 64 + ph);
    }
#pragma unroll
    for (int nt = 0; nt < 4; ++nt) {
      const int r = wn * 64 + nt * 16 + l15;
      b0[nt] = *(const bf16x8*)(s2 + r * 64 + ph);
      if (!SPLIT_A) b1[nt] = *(const bf16x8*)(s1 + r * 64 + ph);
    }
#pragma unroll
    for (int mt = 0; mt < 4; ++mt)
#pragma unroll
      for (int nt = 0; nt < 4; ++nt) {
        acc[mt][nt] = mfma_bf16(a0[mt], b0[nt], acc[mt][nt]);
        if (SPLIT_A)
          acc[mt][nt] = mfma_bf16(a1[mt], b0[nt], acc[mt][nt]);
        else
          acc[mt][nt] = mfma_bf16(a0[mt], b1[nt], acc[mt][nt]);
      }
    __syncthreads();
  }

  // epilogue; C layout: col = lane&15, row = 4*(lane>>4)+j
#pragma unroll
  for (int mt = 0; mt < 4; ++mt)
#pragma unroll
    for (int j = 0; j < 4; ++j) {
      const int gm = mBase + wm * 64 + mt * 16 + q4 * 4 + j;
      if (gm >= M) continue;
      if (EPI == 0) {
        const int b = gm / NTOK;
        const int t = gm - b * NTOK;
#pragma unroll
        for (int nt = 0; nt < 4; ++nt) {
          const int gc = nBase + wn * 64 + nt * 16 + l15;
          float v = acc[mt][nt][j] + bias[gc];
          const int three = gc / 768;
          const int hd = gc - three * 768;
          const int h = hd >> 6, d = hd & 63;
          const int bh = b * 12 + h;
          if (three == 2) {
            o_vt[((size_t)bh * 64 + d) * NKVPAD + t] = __float2bfloat16(v);
          } else {
            if (t > 0) {
              const float pv = acc[mt][nt ^ 2][j] + bias[gc ^ 32];
              const int so = (t - 1) * 64 + d;
              v = v * cosp[so] + ((d < 32) ? -pv : pv) * sinp[so];
            }
            if (three == 0)
              o_q[((size_t)bh * NTOK + t) * 64 + d] = __float2bfloat16(v);
            else  // K: fold softmax scale * log2(e) here (bf16 rel-err scale-invariant)
              o_k[((size_t)bh * NTOK + t) * 64 + d] = __float2bfloat16(v * SCALEL2);
          }
        }
      } else {
#pragma unroll
        for (int nt = 0; nt < 4; ++nt) {
          const int gc = nBase + wn * 64 + nt * 16 + l15;
          o_f32[(size_t)gm * 768 + gc] = acc[mt][nt][j] + bias[gc];
        }
      }
    }
}

// ===== K2: flash attention, 4 waves x 32 q-rows, KV tiles of 64 =====
// Grid: 864 = 8 XCD chunks * 12 heads * 9 q-blocks (XCD-aware remap keeps one
// head's K/V inside one XCD's L2). K is pre-scaled by 64^-0.5*log2e, so QK^T
// emerges in log2 domain. Common path is SHUFFLE-FREE: per-lane col-max +
// __all() implements the defer-max test across the wave; the l-sum is kept as
// per-lane partials and reduced once at the end. Slow path (first tile + rare
// max growth) does the 4-shfl row reduce + rescale. Last KV tile peeled.
__global__ __launch_bounds__(256) void k_attn(
    const __hip_bfloat16* __restrict__ Q, const __hip_bfloat16* __restrict__ Kk,
    const __hip_bfloat16* __restrict__ VT, __hip_bfloat16* __restrict__ ao) {
  __shared__ __hip_bfloat16 Pl[4][32][72]; // per-wave P tile
  const int tid = threadIdx.x, w = tid >> 6, lane = tid & 63;
  const int l15 = lane & 15, q4 = lane >> 4;
  const int id = blockIdx.x;
  const int xcd = id & 7, sub = id >> 3;   // sub 0..107
  const int hh = sub / 9;                  // head-within-xcd 0..11
  const int bh = xcd * 12 + hh;
  const int qb = (sub - hh * 9) * 128 + w * 32;
  const size_t qbase = (size_t)bh * NTOK * 64;
  const __hip_bfloat16* Kb = Kk + qbase;
  const __hip_bfloat16* Vb = VT + (size_t)bh * 64 * NKVPAD;

  // Q fragments (rows clamped; pad rows are discarded at store)
  bf16x8 qa[2][2];
#pragma unroll
  for (int mt = 0; mt < 2; ++mt) {
    int t = qb + mt * 16 + l15;
    if (t > NTOK - 1) t = NTOK - 1;
#pragma unroll
    for (int ks = 0; ks < 2; ++ks)
      qa[mt][ks] = *(const bf16x8*)(Q + qbase + (size_t)t * 64 + ks * 32 + q4 * 8);
  }

  f32x4 accO[2][4] = {};
  float mrun[2][4], lpart[2][4];
#pragma unroll
  for (int mt = 0; mt < 2; ++mt)
#pragma unroll
    for (int j = 0; j < 4; ++j) {
      mrun[mt][j] = -1e30f;
      lpart[mt][j] = 0.0f;
    }

  auto step = [&](int kt, bool last) {
    const int kb0 = kt * 64;
    // S = Q K^T, already in log2 domain (K pre-scaled)
    f32x4 s[2][4] = {};
    {
      bf16x8 kfr[2][4];
#pragma unroll
      for (int nt = 0; nt < 4; ++nt) {
        int krow = kb0 + nt * 16 + l15;
        if (last && krow > NTOK - 1) krow = NTOK - 1;
#pragma unroll
        for (int ks = 0; ks < 2; ++ks)
          kfr[ks][nt] = *(const bf16x8*)(Kb + (size_t)krow * 64 + ks * 32 + q4 * 8);
      }
      __builtin_amdgcn_s_setprio(1);
#pragma unroll
      for (int mt = 0; mt < 2; ++mt)
#pragma unroll
        for (int nt = 0; nt < 4; ++nt)
#pragma unroll
          for (int ks = 0; ks < 2; ++ks)
            s[mt][nt] = mfma_bf16(qa[mt][ks], kfr[ks][nt], s[mt][nt]);
      __builtin_amdgcn_s_setprio(0);
    }
    // mask dead key columns on the peeled tile
    if (last) {
#pragma unroll
      for (int nt = 0; nt < 4; ++nt)
        if (kb0 + nt * 16 + l15 > NTOK - 1) {
#pragma unroll
          for (int mt = 0; mt < 2; ++mt)
#pragma unroll
            for (int j = 0; j < 4; ++j) s[mt][nt][j] = -1e30f;
        }
    }
    // shuffle-free defer-max test: lane-local col max vs mrun+8, __all()
    float smax[2][4];
    bool okl = true;
#pragma unroll
    for (int mt = 0; mt < 2; ++mt)
#pragma unroll
      for (int j = 0; j < 4; ++j) {
        const float a =
            fmaxf(fmaxf(s[mt][0][j], s[mt][1][j]), fmaxf(s[mt][2][j], s[mt][3][j]));
        smax[mt][j] = a;
        okl = okl && (a <= mrun[mt][j] + 8.0f);
      }
    if (!__all((int)okl)) {
      // slow path: true row max via 4-shfl reduce, then rescale state
#pragma unroll
      for (int mt = 0; mt < 2; ++mt)
#pragma unroll
        for (int j = 0; j < 4; ++j) {
          float m0 = smax[mt][j];
#pragma unroll
          for (int off = 1; off < 16; off <<= 1) m0 = fmaxf(m0, __shfl_xor(m0, off));
          const float mnew = fmaxf(mrun[mt][j], m0);
          const float fsc = exp2f(mrun[mt][j] - mnew);
          lpart[mt][j] *= fsc;
          mrun[mt][j] = mnew;
#pragma unroll
          for (int nd = 0; nd < 4; ++nd) accO[mt][nd][j] *= fsc;
        }
    }
    // P = exp2(S - m); per-lane partial sums; stage P to LDS for PV transpose
#pragma unroll
    for (int mt = 0; mt < 2; ++mt)
#pragma unroll
      for (int j = 0; j < 4; ++j) {
        const int row = mt * 16 + q4 * 4 + j;
        float acc = 0.0f;
#pragma unroll
        for (int nt = 0; nt < 4; ++nt) {
          const float p = exp2f(s[mt][nt][j] - mrun[mt][j]);
          acc += p;
          Pl[w][row][nt * 16 + l15] = __float2bfloat16(p);
        }
        lpart[mt][j] += acc;
      }
    // PV (wave-private LDS; compiler orders ds_write->ds_read via lgkmcnt)
    bf16x8 pa[2][2], vf[2][4];
#pragma unroll
    for (int mt = 0; mt < 2; ++mt)
#pragma unroll
      for (int ks = 0; ks < 2; ++ks)
        pa[mt][ks] = *(const bf16x8*)&Pl[w][mt * 16 + l15][ks * 32 + q4 * 8];
#pragma unroll
    for (int nd = 0; nd < 4; ++nd)
#pragma unroll
      for (int ks = 0; ks < 2; ++ks)
        vf[ks][nd] = *(const bf16x8*)(Vb + (size_t)(nd * 16 + l15) * NKVPAD + kb0 +
                                      ks * 32 + q4 * 8);
    __builtin_amdgcn_s_setprio(1);
#pragma unroll
    for (int mt = 0; mt < 2; ++mt)
#pragma unroll
      for (int nd = 0; nd < 4; ++nd)
#pragma unroll
        for (int ks = 0; ks < 2; ++ks)
          accO[mt][nd] = mfma_bf16(pa[mt][ks], vf[ks][nd], accO[mt][nd]);
    __builtin_amdgcn_s_setprio(0);
  };

  for (int kt = 0; kt < 16; ++kt) step(kt, false);
  step(16, true);

  // epilogue: one 4-shfl reduce of the deferred l-sum, then store
  const int b = bh / 12, h = bh - (bh / 12) * 12;
#pragma unroll
  for (int mt = 0; mt < 2; ++mt)
#pragma unroll
    for (int j = 0; j < 4; ++j) {
      float sum = lpart[mt][j];
#pragma unroll
      for (int off = 1; off < 16; off <<= 1) sum += __shfl_xor(sum, off);
      const int t = qb + mt * 16 + q4 * 4 + j;
      if (t > NTOK - 1) continue;
      const float inv = 1.0f / sum;
      const size_t ro = ((size_t)(b * NTOK + t)) * 768 + h * 64;
#pragma unroll
      for (int nd = 0; nd < 4; ++nd) {
        const int d = nd * 16 + l15;
        ao[ro + d] = __float2bfloat16(accO[mt][nd][j] * inv);
      }
    }
}

extern "C" void kernel_launch(void* const* d_in, const int* in_sizes, int n_in,
                              void* d_out, int out_size, void* d_ws, size_t ws_size,
                              hipStream_t stream) {
  const float* x = (const float*)d_in[0];
  const float* sinp = (const float*)d_in[1];
  const float* cosp = (const float*)d_in[2];
  const float* qkvw = (const float*)d_in[3];
  const float* qkvb = (const float*)d_in[4];
  const float* projw = (const float*)d_in[5];
  const float* projb = (const float*)d_in[6];

  char* ws = (char*)d_ws;
  __hip_bfloat16* xhi = (__hip_bfloat16*)(ws + OFF_XHI);
  __hip_bfloat16* xlo = (__hip_bfloat16*)(ws + OFF_XLO);
  __hip_bfloat16* wqhi = (__hip_bfloat16*)(ws + OFF_WQHI);
  __hip_bfloat16* pwhi = (__hip_bfloat16*)(ws + OFF_PWHI);
  __hip_bfloat16* pwlo = (__hip_bfloat16*)(ws + OFF_PWLO);
  __hip_bfloat16* qb = (__hip_bfloat16*)(ws + OFF_Q);
  __hip_bfloat16* kb = (__hip_bfloat16*)(ws + OFF_K);
  __hip_bfloat16* vt = (__hip_bfloat16*)(ws + OFF_VT);
  __hip_bfloat16* ao = (__hip_bfloat16*)(ws + OFF_AO);

  // K0: converts (x gets zero tail to MP rows; qkv_w hi only; proj_w hi+lo)
  {
    int n_src = M * KDIM, n_dst = MP * KDIM;
    k_split<<<(n_dst + 255) / 256, 256, 0, stream>>>(x, xhi, xlo, n_src, n_dst);
    int nw = NQKV * KDIM;
    k_tobf16<<<(nw + 255) / 256, 256, 0, stream>>>(qkvw, wqhi, nw);
    int np = KDIM * KDIM;
    k_split<<<(np + 255) / 256, 256, 0, stream>>>(projw, pwhi, pwlo, np, np);
    int nz = 96 * 64 * (NKVPAD - NTOK);
    k_zero_vt<<<(nz + 255) / 256, 256, 0, stream>>>(vt);
  }
  // K1: QKV GEMM (x split, w single) + bias + RoPE -> q, k(scaled), vT
  k_gemm<0, true><<<dim3(NQKV / 128, MP / 128), 256, 0, stream>>>(
      xhi, xlo, wqhi, qkvb, sinp, cosp, qb, kb, vt, nullptr);
  // K2: flash attention -> attn_out bf16 (864 = 8 XCD * 12 heads * 9 qblocks)
  k_attn<<<dim3(864), 256, 0, stream>>>(qb, kb, vt, ao);
  // K3: proj GEMM (attn_out single, w split) + bias -> fp32 out
  k_gemm<1, false><<<dim3(KDIM / 128, MP / 128), 256, 0, stream>>>(
      ao, pwlo, pwhi, projb, nullptr, nullptr, nullptr, nullptr, nullptr,
      (float*)d_out);
}

// Round 6
// 291.060 us; speedup vs baseline: 1.4202x; 1.1319x over previous
//
#include <hip/hip_runtime.h>
#include <hip/hip_bf16.h>

// ===== Problem constants =====
// B=8, N=1025, C=768, H=12, HD=64
constexpr int NTOK   = 1025;
constexpr int M      = 8 * NTOK;      // 8200 tokens
constexpr int MP     = 8320;          // 65 * 128 padded rows
constexpr int KDIM   = 768;
constexpr int NQKV   = 2304;
constexpr int NKVPAD = 1088;          // 17*64 padded kv length for vT
constexpr float SCALEL2 = 0.125f * 1.44269504f; // 64^-0.5 * log2(e), folded into K

using bf16x8 = __attribute__((ext_vector_type(8))) short;
using f32x4  = __attribute__((ext_vector_type(4))) float;

__device__ __forceinline__ f32x4 mfma_bf16(bf16x8 a, bf16x8 b, f32x4 c) {
  return __builtin_amdgcn_mfma_f32_16x16x32_bf16(a, b, c, 0, 0, 0);
}

__device__ __forceinline__ void gl16(const void* g, void* l) {
  __builtin_amdgcn_global_load_lds(
      (const __attribute__((address_space(1))) void*)g,
      (__attribute__((address_space(3))) void*)l, 16, 0, 0);
}

// ===== Workspace layout (bytes), all 256-aligned =====
constexpr size_t SZ_X     = (size_t)MP * KDIM * 2;        // 12,779,520
constexpr size_t SZ_WQ    = (size_t)NQKV * KDIM * 2;      // 3,538,944
constexpr size_t SZ_PW    = (size_t)KDIM * KDIM * 2;      // 1,179,648
constexpr size_t SZ_QK    = (size_t)96 * NTOK * 64 * 2;   // 12,595,200
constexpr size_t SZ_VT    = (size_t)96 * 64 * NKVPAD * 2; // 13,369,344
constexpr size_t OFF_XHI  = 0;
constexpr size_t OFF_XLO  = OFF_XHI + SZ_X;
constexpr size_t OFF_WQHI = OFF_XLO + SZ_X;
constexpr size_t OFF_PWHI = OFF_WQHI + SZ_WQ;
constexpr size_t OFF_PWLO = OFF_PWHI + SZ_PW;
constexpr size_t OFF_Q    = OFF_PWLO + SZ_PW;
constexpr size_t OFF_K    = OFF_Q + SZ_QK;
constexpr size_t OFF_VT   = OFF_K + SZ_QK;
constexpr size_t OFF_AO   = OFF_VT + SZ_VT;
// total ~83 MB

// ===== K0a: fp32 -> (hi,lo) bf16 split, zero tail =====
__global__ void k_split(const float* __restrict__ src, __hip_bfloat16* __restrict__ hi,
                        __hip_bfloat16* __restrict__ lo, int n_src, int n_dst) {
  int i = blockIdx.x * 256 + threadIdx.x;
  if (i >= n_dst) return;
  float v = (i < n_src) ? src[i] : 0.0f;
  __hip_bfloat16 h = __float2bfloat16(v);
  hi[i] = h;
  lo[i] = __float2bfloat16(v - __bfloat162float(h));
}

// K0b: fp32 -> bf16 (hi only)
__global__ void k_tobf16(const float* __restrict__ src, __hip_bfloat16* __restrict__ dst,
                         int n) {
  int i = blockIdx.x * 256 + threadIdx.x;
  if (i >= n) return;
  dst[i] = __float2bfloat16(src[i]);
}

// zero vT pad columns (keys 1025..1087) so PV MFMA never sees NaN garbage
__global__ void k_zero_vt(__hip_bfloat16* __restrict__ vt) {
  int i = blockIdx.x * 256 + threadIdx.x;
  constexpr int NPADC = NKVPAD - NTOK; // 63
  if (i >= 96 * 64 * NPADC) return;
  int r = i / NPADC;
  int c = NTOK + (i - r * NPADC);
  vt[(size_t)r * NKVPAD + c] = __float2bfloat16(0.0f);
}

// ===== GEMM core: 128x128 tile, BK=32, 2-term split, swizzled LDS =====
// 2-phase double-buffered staging: stage(t+1) is issued BEFORE compute(t);
// the single __syncthreads per step drains only the latency tail that the
// 32 MFMAs + 12 ds_read_b128 didn't already cover (T3 minimal recipe).
// SPLIT_A=1: acc = Ah*Bh + Al*Bh   (Asec = A_lo, row base mBase)
// SPLIT_A=0: acc = Ah*Bh + Ah*Bl   (Asec = B_lo, row base nBase)
// LDS swizzle (conflict-free ds_read_b128 with linear global_load_lds dest):
//   chunk c (16B) holds global (row=c>>2, slot=(c&3)^((row>>1)&3)) of the tile;
//   4-lane groups still fetch the same contiguous 64B from global (coalesced).
// EPI=0: QKV -> bias + RoPE -> q,k ([bh][t][d] bf16; K pre-scaled by SCALEL2)
//        and vT ([bh][d][t_pad] bf16)
// EPI=1: proj -> bias -> fp32 d_out
template <int EPI, bool SPLIT_A>
__global__ __launch_bounds__(256) void k_gemm(
    const __hip_bfloat16* __restrict__ Ahi, const __hip_bfloat16* __restrict__ Asec,
    const __hip_bfloat16* __restrict__ Bhi, const float* __restrict__ bias,
    const float* __restrict__ sinp, const float* __restrict__ cosp,
    __hip_bfloat16* __restrict__ o_q, __hip_bfloat16* __restrict__ o_k,
    __hip_bfloat16* __restrict__ o_vt, float* __restrict__ o_f32) {
  const int tid = threadIdx.x;
  const int w = tid >> 6, lane = tid & 63;
  const int wm = w >> 1, wn = w & 1;
  const int l15 = lane & 15, q4 = lane >> 4;
  const int mBase = blockIdx.y * 128, nBase = blockIdx.x * 128;

  __shared__ __hip_bfloat16 sm[2][3 * 4096]; // 2 bufs x three [128][32] tiles

  const char* p0 = (const char*)Ahi + (size_t)mBase * (KDIM * 2);
  const char* p1 = (const char*)Asec + (size_t)(SPLIT_A ? mBase : nBase) * (KDIM * 2);
  const char* p2 = (const char*)Bhi + (size_t)nBase * (KDIM * 2);

  const int slog = ((tid & 3) ^ ((tid >> 3) & 3)) << 4; // staged slot byte offset
  const int ph = ((q4 ^ ((l15 >> 1) & 3)) << 4);        // fragment slot byte offset

  auto stage = [&](int kt, int buf) {
    const int kofs = kt * 64; // bytes into each row
    char* base = (char*)sm[buf];
#pragma unroll
    for (int i = 0; i < 2; ++i) {
      const int c = i * 256 + tid; // 16B chunk index, 512 per tile
      const size_t rb = (size_t)(i * 64 + (tid >> 2)) * (KDIM * 2) + slog + kofs;
      gl16(p0 + rb, base + (size_t)c * 16);
      gl16(p1 + rb, base + 8192 + (size_t)c * 16);
      gl16(p2 + rb, base + 16384 + (size_t)c * 16);
    }
  };

  f32x4 acc[4][4] = {};

  stage(0, 0);
  __syncthreads();

  constexpr int NKT = KDIM / 32; // 24
  for (int kt = 0; kt < NKT; ++kt) {
    const int cur = kt & 1;
    if (kt + 1 < NKT) stage(kt + 1, cur ^ 1); // async; flies under compute
    char* s0 = (char*)sm[cur];
    char* s1 = s0 + 8192;
    char* s2 = s0 + 16384;
    bf16x8 a0[4], a1[4], b0[4], b1[4];
#pragma unroll
    for (int mt = 0; mt < 4; ++mt) {
      const int r = wm * 64 + mt * 16 + l15;
      a0[mt] = *(const bf16x8*)(s0 + r * 64 + ph);
      if (SPLIT_A) a1[mt] = *(const bf16x8*)(s1 + r * 64 + ph);
    }
#pragma unroll
    for (int nt = 0; nt < 4; ++nt) {
      const int r = wn * 64 + nt * 16 + l15;
      b0[nt] = *(const bf16x8*)(s2 + r * 64 + ph);
      if (!SPLIT_A) b1[nt] = *(const bf16x8*)(s1 + r * 64 + ph);
    }
    __builtin_amdgcn_s_setprio(1);
#pragma unroll
    for (int mt = 0; mt < 4; ++mt)
#pragma unroll
      for (int nt = 0; nt < 4; ++nt) {
        acc[mt][nt] = mfma_bf16(a0[mt], b0[nt], acc[mt][nt]);
        if (SPLIT_A)
          acc[mt][nt] = mfma_bf16(a1[mt], b0[nt], acc[mt][nt]);
        else
          acc[mt][nt] = mfma_bf16(a0[mt], b1[nt], acc[mt][nt]);
      }
    __builtin_amdgcn_s_setprio(0);
    __syncthreads(); // drains vmcnt -> buf[cur^1] complete; buf[cur] reusable
  }

  // epilogue; C layout: col = lane&15, row = 4*(lane>>4)+j
#pragma unroll
  for (int mt = 0; mt < 4; ++mt)
#pragma unroll
    for (int j = 0; j < 4; ++j) {
      const int gm = mBase + wm * 64 + mt * 16 + q4 * 4 + j;
      if (gm >= M) continue;
      if (EPI == 0) {
        const int b = gm / NTOK;
        const int t = gm - b * NTOK;
#pragma unroll
        for (int nt = 0; nt < 4; ++nt) {
          const int gc = nBase + wn * 64 + nt * 16 + l15;
          float v = acc[mt][nt][j] + bias[gc];
          const int three = gc / 768;
          const int hd = gc - three * 768;
          const int h = hd >> 6, d = hd & 63;
          const int bh = b * 12 + h;
          if (three == 2) {
            o_vt[((size_t)bh * 64 + d) * NKVPAD + t] = __float2bfloat16(v);
          } else {
            if (t > 0) {
              const float pv = acc[mt][nt ^ 2][j] + bias[gc ^ 32];
              const int so = (t - 1) * 64 + d;
              v = v * cosp[so] + ((d < 32) ? -pv : pv) * sinp[so];
            }
            if (three == 0)
              o_q[((size_t)bh * NTOK + t) * 64 + d] = __float2bfloat16(v);
            else  // K: fold softmax scale * log2(e) here (bf16 rel-err scale-invariant)
              o_k[((size_t)bh * NTOK + t) * 64 + d] = __float2bfloat16(v * SCALEL2);
          }
        }
      } else {
#pragma unroll
        for (int nt = 0; nt < 4; ++nt) {
          const int gc = nBase + wn * 64 + nt * 16 + l15;
          o_f32[(size_t)gm * 768 + gc] = acc[mt][nt][j] + bias[gc];
        }
      }
    }
}

// ===== K2: flash attention, 4 waves x 32 q-rows, KV tiles of 64 =====
// Grid: 864 = 8 XCD chunks * 12 heads * 9 q-blocks (XCD-aware remap keeps one
// head's K/V inside one XCD's L2). K is pre-scaled by 64^-0.5*log2e, so QK^T
// emerges in log2 domain. Common path is SHUFFLE-FREE: per-lane col-max +
// __all() implements the defer-max test across the wave; the l-sum is kept as
// per-lane partials and reduced once at the end. Slow path (first tile + rare
// max growth) does the 4-shfl row reduce + rescale. Last KV tile peeled.
__global__ __launch_bounds__(256) void k_attn(
    const __hip_bfloat16* __restrict__ Q, const __hip_bfloat16* __restrict__ Kk,
    const __hip_bfloat16* __restrict__ VT, __hip_bfloat16* __restrict__ ao) {
  __shared__ __hip_bfloat16 Pl[4][32][72]; // per-wave P tile
  const int tid = threadIdx.x, w = tid >> 6, lane = tid & 63;
  const int l15 = lane & 15, q4 = lane >> 4;
  const int id = blockIdx.x;
  const int xcd = id & 7, sub = id >> 3;   // sub 0..107
  const int hh = sub / 9;                  // head-within-xcd 0..11
  const int bh = xcd * 12 + hh;
  const int qb = (sub - hh * 9) * 128 + w * 32;
  const size_t qbase = (size_t)bh * NTOK * 64;
  const __hip_bfloat16* Kb = Kk + qbase;
  const __hip_bfloat16* Vb = VT + (size_t)bh * 64 * NKVPAD;

  // Q fragments (rows clamped; pad rows are discarded at store)
  bf16x8 qa[2][2];
#pragma unroll
  for (int mt = 0; mt < 2; ++mt) {
    int t = qb + mt * 16 + l15;
    if (t > NTOK - 1) t = NTOK - 1;
#pragma unroll
    for (int ks = 0; ks < 2; ++ks)
      qa[mt][ks] = *(const bf16x8*)(Q + qbase + (size_t)t * 64 + ks * 32 + q4 * 8);
  }

  f32x4 accO[2][4] = {};
  float mrun[2][4], lpart[2][4];
#pragma unroll
  for (int mt = 0; mt < 2; ++mt)
#pragma unroll
    for (int j = 0; j < 4; ++j) {
      mrun[mt][j] = -1e30f;
      lpart[mt][j] = 0.0f;
    }

  auto step = [&](int kt, bool last) {
    const int kb0 = kt * 64;
    // S = Q K^T, already in log2 domain (K pre-scaled)
    f32x4 s[2][4] = {};
    {
      bf16x8 kfr[2][4];
#pragma unroll
      for (int nt = 0; nt < 4; ++nt) {
        int krow = kb0 + nt * 16 + l15;
        if (last && krow > NTOK - 1) krow = NTOK - 1;
#pragma unroll
        for (int ks = 0; ks < 2; ++ks)
          kfr[ks][nt] = *(const bf16x8*)(Kb + (size_t)krow * 64 + ks * 32 + q4 * 8);
      }
      __builtin_amdgcn_s_setprio(1);
#pragma unroll
      for (int mt = 0; mt < 2; ++mt)
#pragma unroll
        for (int nt = 0; nt < 4; ++nt)
#pragma unroll
          for (int ks = 0; ks < 2; ++ks)
            s[mt][nt] = mfma_bf16(qa[mt][ks], kfr[ks][nt], s[mt][nt]);
      __builtin_amdgcn_s_setprio(0);
    }
    // mask dead key columns on the peeled tile
    if (last) {
#pragma unroll
      for (int nt = 0; nt < 4; ++nt)
        if (kb0 + nt * 16 + l15 > NTOK - 1) {
#pragma unroll
          for (int mt = 0; mt < 2; ++mt)
#pragma unroll
            for (int j = 0; j < 4; ++j) s[mt][nt][j] = -1e30f;
        }
    }
    // shuffle-free defer-max test: lane-local col max vs mrun+8, __all()
    float smax[2][4];
    bool okl = true;
#pragma unroll
    for (int mt = 0; mt < 2; ++mt)
#pragma unroll
      for (int j = 0; j < 4; ++j) {
        const float a =
            fmaxf(fmaxf(s[mt][0][j], s[mt][1][j]), fmaxf(s[mt][2][j], s[mt][3][j]));
        smax[mt][j] = a;
        okl = okl && (a <= mrun[mt][j] + 8.0f);
      }
    if (!__all((int)okl)) {
      // slow path: true row max via 4-shfl reduce, then rescale state
#pragma unroll
      for (int mt = 0; mt < 2; ++mt)
#pragma unroll
        for (int j = 0; j < 4; ++j) {
          float m0 = smax[mt][j];
#pragma unroll
          for (int off = 1; off < 16; off <<= 1) m0 = fmaxf(m0, __shfl_xor(m0, off));
          const float mnew = fmaxf(mrun[mt][j], m0);
          const float fsc = exp2f(mrun[mt][j] - mnew);
          lpart[mt][j] *= fsc;
          mrun[mt][j] = mnew;
#pragma unroll
          for (int nd = 0; nd < 4; ++nd) accO[mt][nd][j] *= fsc;
        }
    }
    // P = exp2(S - m); per-lane partial sums; stage P to LDS for PV transpose
#pragma unroll
    for (int mt = 0; mt < 2; ++mt)
#pragma unroll
      for (int j = 0; j < 4; ++j) {
        const int row = mt * 16 + q4 * 4 + j;
        float acc = 0.0f;
#pragma unroll
        for (int nt = 0; nt < 4; ++nt) {
          const float p = exp2f(s[mt][nt][j] - mrun[mt][j]);
          acc += p;
          Pl[w][row][nt * 16 + l15] = __float2bfloat16(p);
        }
        lpart[mt][j] += acc;
      }
    // PV (wave-private LDS; compiler orders ds_write->ds_read via lgkmcnt)
    bf16x8 pa[2][2], vf[2][4];
#pragma unroll
    for (int mt = 0; mt < 2; ++mt)
#pragma unroll
      for (int ks = 0; ks < 2; ++ks)
        pa[mt][ks] = *(const bf16x8*)&Pl[w][mt * 16 + l15][ks * 32 + q4 * 8];
#pragma unroll
    for (int nd = 0; nd < 4; ++nd)
#pragma unroll
      for (int ks = 0; ks < 2; ++ks)
        vf[ks][nd] = *(const bf16x8*)(Vb + (size_t)(nd * 16 + l15) * NKVPAD + kb0 +
                                      ks * 32 + q4 * 8);
    __builtin_amdgcn_s_setprio(1);
#pragma unroll
    for (int mt = 0; mt < 2; ++mt)
#pragma unroll
      for (int nd = 0; nd < 4; ++nd)
#pragma unroll
        for (int ks = 0; ks < 2; ++ks)
          accO[mt][nd] = mfma_bf16(pa[mt][ks], vf[ks][nd], accO[mt][nd]);
    __builtin_amdgcn_s_setprio(0);
  };

  for (int kt = 0; kt < 16; ++kt) step(kt, false);
  step(16, true);

  // epilogue: one 4-shfl reduce of the deferred l-sum, then store
  const int b = bh / 12, h = bh - (bh / 12) * 12;
#pragma unroll
  for (int mt = 0; mt < 2; ++mt)
#pragma unroll
    for (int j = 0; j < 4; ++j) {
      float sum = lpart[mt][j];
#pragma unroll
      for (int off = 1; off < 16; off <<= 1) sum += __shfl_xor(sum, off);
      const int t = qb + mt * 16 + q4 * 4 + j;
      if (t > NTOK - 1) continue;
      const float inv = 1.0f / sum;
      const size_t ro = ((size_t)(b * NTOK + t)) * 768 + h * 64;
#pragma unroll
      for (int nd = 0; nd < 4; ++nd) {
        const int d = nd * 16 + l15;
        ao[ro + d] = __float2bfloat16(accO[mt][nd][j] * inv);
      }
    }
}

extern "C" void kernel_launch(void* const* d_in, const int* in_sizes, int n_in,
                              void* d_out, int out_size, void* d_ws, size_t ws_size,
                              hipStream_t stream) {
  const float* x = (const float*)d_in[0];
  const float* sinp = (const float*)d_in[1];
  const float* cosp = (const float*)d_in[2];
  const float* qkvw = (const float*)d_in[3];
  const float* qkvb = (const float*)d_in[4];
  const float* projw = (const float*)d_in[5];
  const float* projb = (const float*)d_in[6];

  char* ws = (char*)d_ws;
  __hip_bfloat16* xhi = (__hip_bfloat16*)(ws + OFF_XHI);
  __hip_bfloat16* xlo = (__hip_bfloat16*)(ws + OFF_XLO);
  __hip_bfloat16* wqhi = (__hip_bfloat16*)(ws + OFF_WQHI);
  __hip_bfloat16* pwhi = (__hip_bfloat16*)(ws + OFF_PWHI);
  __hip_bfloat16* pwlo = (__hip_bfloat16*)(ws + OFF_PWLO);
  __hip_bfloat16* qb = (__hip_bfloat16*)(ws + OFF_Q);
  __hip_bfloat16* kb = (__hip_bfloat16*)(ws + OFF_K);
  __hip_bfloat16* vt = (__hip_bfloat16*)(ws + OFF_VT);
  __hip_bfloat16* ao = (__hip_bfloat16*)(ws + OFF_AO);

  // K0: converts (x gets zero tail to MP rows; qkv_w hi only; proj_w hi+lo)
  {
    int n_src = M * KDIM, n_dst = MP * KDIM;
    k_split<<<(n_dst + 255) / 256, 256, 0, stream>>>(x, xhi, xlo, n_src, n_dst);
    int nw = NQKV * KDIM;
    k_tobf16<<<(nw + 255) / 256, 256, 0, stream>>>(qkvw, wqhi, nw);
    int np = KDIM * KDIM;
    k_split<<<(np + 255) / 256, 256, 0, stream>>>(projw, pwhi, pwlo, np, np);
    int nz = 96 * 64 * (NKVPAD - NTOK);
    k_zero_vt<<<(nz + 255) / 256, 256, 0, stream>>>(vt);
  }
  // K1: QKV GEMM (x split, w single) + bias + RoPE -> q, k(scaled), vT
  k_gemm<0, true><<<dim3(NQKV / 128, MP / 128), 256, 0, stream>>>(
      xhi, xlo, wqhi, qkvb, sinp, cosp, qb, kb, vt, nullptr);
  // K2: flash attention -> attn_out bf16 (864 = 8 XCD * 12 heads * 9 qblocks)
  k_attn<<<dim3(864), 256, 0, stream>>>(qb, kb, vt, ao);
  // K3: proj GEMM (attn_out single, w split) + bias -> fp32 out
  k_gemm<1, false><<<dim3(KDIM / 128, MP / 128), 256, 0, stream>>>(
      ao, pwlo, pwhi, projb, nullptr, nullptr, nullptr, nullptr, nullptr,
      (float*)d_out);
}